// Round 6
// baseline (251.946 us; speedup 1.0000x reference)
//
#include <hip/hip_runtime.h>
#include <cstdint>
#include <cstddef>

// Problem constants
constexpr int B = 64, S = 2048, H = 512, E = 256, V = 32000;
constexpr int NCHUNK = 32;   // attention: 32 chunks of 64 keys per batch

// ---------------------------------------------------------------------------
// Kernel 1: fused scores + online-softmax partials (enc read exactly once).
// One wave per (b, 64-key chunk); lane covers 8 of 512 dims (2 float4 slices).
// INSTRUMENTED: body runs twice (rep loop, identical writes) so this dispatch
// exceeds the 150 µs harness fills and surfaces in the top-5 with counters.
// ---------------------------------------------------------------------------
__global__ __launch_bounds__(256) void attn_part_kernel(
    const float* __restrict__ hd, const float* __restrict__ enc,
    float* __restrict__ m_part, float* __restrict__ l_part,
    float* __restrict__ acc_part)
{
    for (int rep = 0; rep < 2; ++rep) {
    int b = blockIdx.x >> 3;
    int wave = threadIdx.x >> 6, lane = threadIdx.x & 63;
    int chunk = ((blockIdx.x & 7) << 2) + wave;
    int s0 = chunk * 64;

    const float4* hv = (const float4*)(hd + (size_t)b * H);
    float4 h0 = hv[lane], h1 = hv[64 + lane];
    const float4* ev = (const float4*)(enc + (size_t)b * S * H) + (size_t)s0 * (H / 4);

    float4 e0 = ev[lane], e1 = ev[64 + lane];
    float p = e0.x * h0.x + e0.y * h0.y + e0.z * h0.z + e0.w * h0.w
            + e1.x * h1.x + e1.y * h1.y + e1.z * h1.z + e1.w * h1.w;
#pragma unroll
    for (int off = 32; off; off >>= 1) p += __shfl_xor(p, off, 64);
    float m = p, l = 1.f;
    float4 a0 = e0, a1 = e1;

    for (int s = 1; s < 64; ++s) {
        const float4* row = ev + (size_t)s * (H / 4);
        e0 = row[lane]; e1 = row[64 + lane];
        p = e0.x * h0.x + e0.y * h0.y + e0.z * h0.z + e0.w * h0.w
          + e1.x * h1.x + e1.y * h1.y + e1.z * h1.z + e1.w * h1.w;
#pragma unroll
        for (int off = 32; off; off >>= 1) p += __shfl_xor(p, off, 64);
        if (p <= m) {
            float w = __expf(p - m);
            l += w;
            a0.x += w * e0.x; a0.y += w * e0.y; a0.z += w * e0.z; a0.w += w * e0.w;
            a1.x += w * e1.x; a1.y += w * e1.y; a1.z += w * e1.z; a1.w += w * e1.w;
        } else {
            float sc = __expf(m - p);
            m = p;
            l = l * sc + 1.f;
            a0.x = a0.x * sc + e0.x; a0.y = a0.y * sc + e0.y;
            a0.z = a0.z * sc + e0.z; a0.w = a0.w * sc + e0.w;
            a1.x = a1.x * sc + e1.x; a1.y = a1.y * sc + e1.y;
            a1.z = a1.z * sc + e1.z; a1.w = a1.w * sc + e1.w;
        }
    }

    int base = b * NCHUNK + chunk;
    if (lane == 0) { m_part[base] = m; l_part[base] = l; }
    float4* ap = (float4*)(acc_part + (size_t)base * H);
    ap[lane] = a0; ap[64 + lane] = a1;
    }
}

// ---------------------------------------------------------------------------
// Kernel 2: combine partials -> ctx; embedding gather; transposed LSTM input
// inp_t[k][b]: [0,256)=xe, [256,768)=ctx, [768,1280)=h0. (unchanged)
// ---------------------------------------------------------------------------
__global__ __launch_bounds__(256) void combine_kernel(
    const float* __restrict__ m_part, const float* __restrict__ l_part,
    const float* __restrict__ acc_part, const int* __restrict__ x,
    const float* __restrict__ emb, const float* __restrict__ h0,
    float* __restrict__ inp_t)
{
    int b = blockIdx.x, t = threadIdx.x;
    float M = -1e30f;
    for (int i = 0; i < NCHUNK; ++i) M = fmaxf(M, m_part[b * NCHUNK + i]);
    float L = 0.f;
    for (int i = 0; i < NCHUNK; ++i)
        L += l_part[b * NCHUNK + i] * __expf(m_part[b * NCHUNK + i] - M);
    float invL = 1.f / L;

    for (int d = t; d < H; d += 256) {
        float s = 0.f;
        for (int i = 0; i < NCHUNK; ++i)
            s += __expf(m_part[b * NCHUNK + i] - M) *
                 acc_part[((size_t)(b * NCHUNK + i)) * H + d];
        inp_t[(E + d) * B + b] = s * invL;
    }
    inp_t[t * B + b] = emb[(size_t)x[b] * E + t];
    for (int d = t; d < H; d += 256)
        inp_t[(E + H + d) * B + b] = h0[b * H + d];
}

// ---------------------------------------------------------------------------
// Kernel 3: fully-fused LSTM layer (proven round-5 version, unchanged).
// ---------------------------------------------------------------------------
__global__ __launch_bounds__(256) void lstm_fused_kernel(
    const float* __restrict__ A1, int lda1, int k1len,
    const float* __restrict__ A2, int lda2, int KT,
    const float* __restrict__ X,
    const float* __restrict__ b_ih, const float* __restrict__ b_hh,
    const float* __restrict__ c_prev,
    float* __restrict__ h_t, float* __restrict__ out_h, float* __restrict__ out_c)
{
    __shared__ float sm[4 * 32 * 20 + 4 * 32 * 64];   // As | Xs  (42.5 KB)
    float (*As)[32][20] = (float(*)[32][20])sm;
    float (*Xs)[32][64] = (float(*)[32][64])(sm + 4 * 32 * 20);
    float (*Ps)[16][64] = (float(*)[16][64])(sm + 4 * 32 * 20); // aliases Xs

    const int t = threadIdx.x;
    const int j0 = blockIdx.x * 4;
    const int QK = KT >> 2;
    const int nIter = QK >> 5;

    const int kq = t >> 6, r = t & 63, ty = r >> 4, tx = r & 15;

    float acc[4][4];
#pragma unroll
    for (int i = 0; i < 4; ++i)
#pragma unroll
        for (int j = 0; j < 4; ++j) acc[i][j] = 0.f;

    for (int it = 0; it < nIter; ++it) {
#pragma unroll
        for (int q = 0; q < 2; ++q) {
            int p = t + q * 256;
            int il = p >> 5, c = p & 31;
            int akq = c >> 3, k4 = (c & 7) * 4;
            int gk = akq * QK + it * 32 + k4;
            int grow = j0 + (il & 3) + 512 * (il >> 2);
            const float* src = (gk < k1len)
                ? A1 + (size_t)grow * lda1 + gk
                : A2 + (size_t)grow * lda2 + (gk - k1len);
            float4 v = *(const float4*)src;
            As[akq][k4 + 0][il] = v.x; As[akq][k4 + 1][il] = v.y;
            As[akq][k4 + 2][il] = v.z; As[akq][k4 + 3][il] = v.w;
        }
#pragma unroll
        for (int q = 0; q < 8; ++q) {
            int p = t + q * 256;
            int kk_all = p >> 4, col = (p & 15) * 4;
            int xkq = kk_all >> 5, kk = kk_all & 31;
            int gk = xkq * QK + it * 32 + kk;
            *(float4*)&Xs[xkq][kk][col] = *(const float4*)&X[(size_t)gk * 64 + col];
        }
        __syncthreads();

#pragma unroll 8
        for (int kk = 0; kk < 32; ++kk) {
            float4 av = *(const float4*)&As[kq][kk][ty * 4];
            float4 xv = *(const float4*)&Xs[kq][kk][tx * 4];
            float aa[4] = {av.x, av.y, av.z, av.w};
            float xx[4] = {xv.x, xv.y, xv.z, xv.w};
#pragma unroll
            for (int i = 0; i < 4; ++i)
#pragma unroll
                for (int j = 0; j < 4; ++j) acc[i][j] += aa[i] * xx[j];
        }
        __syncthreads();
    }

#pragma unroll
    for (int i = 0; i < 4; ++i)
        *(float4*)&Ps[kq][ty * 4 + i][tx * 4] =
            make_float4(acc[i][0], acc[i][1], acc[i][2], acc[i][3]);
    __syncthreads();

    for (int idx = t; idx < 16 * 64; idx += 256) {
        int row = idx >> 6, b = idx & 63;
        Ps[0][row][b] = Ps[0][row][b] + Ps[1][row][b] + Ps[2][row][b] + Ps[3][row][b];
    }
    __syncthreads();

    {
        int jj = t >> 6, b = t & 63;
        int j = j0 + jj;
        float gi = Ps[0][jj][b]      + b_ih[j]        + b_hh[j];
        float gf = Ps[0][4 + jj][b]  + b_ih[j + 512]  + b_hh[j + 512];
        float gg = Ps[0][8 + jj][b]  + b_ih[j + 1024] + b_hh[j + 1024];
        float go = Ps[0][12 + jj][b] + b_ih[j + 1536] + b_hh[j + 1536];
        float iv = 1.f / (1.f + __expf(-gi));
        float fv = 1.f / (1.f + __expf(-gf));
        float gv = tanhf(gg);
        float ov = 1.f / (1.f + __expf(-go));
        float cp = c_prev ? c_prev[b * H + j] : 0.f;
        float c2 = fv * cp + iv * gv;
        float hv = ov * tanhf(c2);
        h_t[j * B + b] = hv;
        if (out_h) { out_h[b * H + j] = hv; out_c[b * H + j] = c2; }
    }
}

// ---------------------------------------------------------------------------
// Kernel 4 (v3): fc logits. A (fc_w) has ZERO reuse -> stream it directly
// from global with per-lane-distinct dwordx4 vector loads + distance-2
// register prefetch (no LDS round-trip). Only X (z, 128 KB) is LDS-staged,
// in two 64 KB half-tiles. BM=64, TM=8, TN=2, 256 thr, 500 blocks (2/CU).
// VALU-bound floor ~13.7 us; LDS traffic cut ~5x vs previous version.
// ---------------------------------------------------------------------------
__global__ __launch_bounds__(256) void fc_gemm_kernel(
    const float* __restrict__ A, const float* __restrict__ X,
    float* __restrict__ outp, const float* __restrict__ bias)
{
    __shared__ float Xs[256][64];          // 64 KB half-tile of X

    const int t = threadIdx.x;
    const int tx = t & 31;                 // col group: cols 2*tx, 2*tx+1
    const int ty = t >> 5;                 // row group: rows m0+8*ty .. +7
    const int m0 = blockIdx.x * 64;
    const float* Arow = A + (size_t)(m0 + ty * 8) * 512;

    float acc[8][2];
#pragma unroll
    for (int i = 0; i < 8; ++i) { acc[i][0] = 0.f; acc[i][1] = 0.f; }

    float4 a0[8], a1[8];
#pragma unroll
    for (int i = 0; i < 8; ++i) a0[i] = *(const float4*)(Arow + (size_t)i * 512 + 0);
#pragma unroll
    for (int i = 0; i < 8; ++i) a1[i] = *(const float4*)(Arow + (size_t)i * 512 + 4);

    for (int ph = 0; ph < 2; ++ph) {
        __syncthreads();                   // previous half-tile fully consumed
        // stage X half-tile: k in [ph*256, ph*256+256)
#pragma unroll
        for (int q = 0; q < 16; ++q) {
            int p = t + q * 256;
            int row = p >> 4, col = (p & 15) * 4;
            *(float4*)&Xs[row][col] =
                *(const float4*)&X[(size_t)(ph * 256 + row) * 64 + col];
        }
        __syncthreads();

        for (int kk = 0; kk < 256; kk += 4) {
            float4 cur[8];
#pragma unroll
            for (int i = 0; i < 8; ++i) cur[i] = a0[i];
#pragma unroll
            for (int i = 0; i < 8; ++i) a0[i] = a1[i];
            int gnext = ph * 256 + kk + 8;
            if (gnext < 512) {
#pragma unroll
                for (int i = 0; i < 8; ++i)
                    a1[i] = *(const float4*)(Arow + (size_t)i * 512 + gnext);
            }
            float2 xv0 = *(const float2*)&Xs[kk + 0][tx * 2];
            float2 xv1 = *(const float2*)&Xs[kk + 1][tx * 2];
            float2 xv2 = *(const float2*)&Xs[kk + 2][tx * 2];
            float2 xv3 = *(const float2*)&Xs[kk + 3][tx * 2];
#pragma unroll
            for (int i = 0; i < 8; ++i) {
                acc[i][0] += cur[i].x * xv0.x; acc[i][1] += cur[i].x * xv0.y;
                acc[i][0] += cur[i].y * xv1.x; acc[i][1] += cur[i].y * xv1.y;
                acc[i][0] += cur[i].z * xv2.x; acc[i][1] += cur[i].z * xv2.y;
                acc[i][0] += cur[i].w * xv3.x; acc[i][1] += cur[i].w * xv3.y;
            }
        }
    }

    // epilogue: out[b][v] for b = 2*tx+j, v = m0+8*ty .. +7
#pragma unroll
    for (int j = 0; j < 2; ++j) {
        int b = tx * 2 + j;
        int v0 = m0 + ty * 8;
        float4 w0, w1;
        w0.x = acc[0][j] + bias[v0 + 0]; w0.y = acc[1][j] + bias[v0 + 1];
        w0.z = acc[2][j] + bias[v0 + 2]; w0.w = acc[3][j] + bias[v0 + 3];
        w1.x = acc[4][j] + bias[v0 + 4]; w1.y = acc[5][j] + bias[v0 + 5];
        w1.z = acc[6][j] + bias[v0 + 6]; w1.w = acc[7][j] + bias[v0 + 7];
        *(float4*)&outp[(size_t)b * V + v0] = w0;
        *(float4*)&outp[(size_t)b * V + v0 + 4] = w1;
    }
}

// ---------------------------------------------------------------------------
extern "C" void kernel_launch(void* const* d_in, const int* in_sizes, int n_in,
                              void* d_out, int out_size, void* d_ws, size_t ws_size,
                              hipStream_t stream)
{
    const int*   x     = (const int*)d_in[0];
    const float* hdec  = (const float*)d_in[1];
    const float* enc   = (const float*)d_in[2];
    const float* h0    = (const float*)d_in[3];
    const float* c0    = (const float*)d_in[4];
    const float* emb   = (const float*)d_in[5];
    const float* w_ih1 = (const float*)d_in[6];
    const float* w_hh1 = (const float*)d_in[7];
    const float* b_ih1 = (const float*)d_in[8];
    const float* b_hh1 = (const float*)d_in[9];
    const float* w_ih  = (const float*)d_in[10];
    // d_in[11] = w_hh: multiplied by zero hidden state in layers 2-4 -> skipped
    const float* b_ih  = (const float*)d_in[12];
    const float* b_hh  = (const float*)d_in[13];
    const float* fc_w  = (const float*)d_in[14];
    const float* fc_b  = (const float*)d_in[15];

    float* out = (float*)d_out;
    float* ws  = (float*)d_ws;

    float* m_part   = ws;                                // 2048
    float* l_part   = ws + 2048;                         // 2048
    float* acc_part = ws + 4096;                         // 64*32*512
    float* inp_t    = acc_part + (size_t)B * NCHUNK * H; // 1280*64
    float* zA       = inp_t + 1280 * B;                  // 512*64
    float* zB       = zA + H * B;                        // 512*64

    float* out_h = out + (size_t)B * V;
    float* out_c = out_h + (size_t)B * H;

    // 1) attention (enc read once per rep; x2 instrumentation)
    attn_part_kernel<<<512, 256, 0, stream>>>(hdec, enc, m_part, l_part, acc_part);
    combine_kernel<<<64, 256, 0, stream>>>(m_part, l_part, acc_part, x, emb, h0, inp_t);

    // 2) LSTM layer 1: K = 768 (w_ih1) | 512 (w_hh1) = 1280, real c0
    lstm_fused_kernel<<<128, 256, 0, stream>>>(
        w_ih1, 768, 768, w_hh1, 512, 1280, inp_t,
        b_ih1, b_hh1, c0, zA, nullptr, nullptr);

    // 3) LSTM layers 2-4 (zero h/c: only w_ih contributes), K = 512
    lstm_fused_kernel<<<128, 256, 0, stream>>>(
        w_ih + 0 * (size_t)2048 * H, 512, 512, nullptr, 0, 512, zA,
        b_ih + 0 * 2048, b_hh + 0 * 2048, nullptr, zB, nullptr, nullptr);
    lstm_fused_kernel<<<128, 256, 0, stream>>>(
        w_ih + 1 * (size_t)2048 * H, 512, 512, nullptr, 0, 512, zB,
        b_ih + 1 * 2048, b_hh + 1 * 2048, nullptr, zA, nullptr, nullptr);
    lstm_fused_kernel<<<128, 256, 0, stream>>>(
        w_ih + 2 * (size_t)2048 * H, 512, 512, nullptr, 0, 512, zA,
        b_ih + 2 * 2048, b_hh + 2 * 2048, nullptr, zB, out_h, out_c);

    // 4) logits = zB^T @ fc_w^T + fc_b  (A streamed from global, X in LDS)
    fc_gemm_kernel<<<500, 256, 0, stream>>>(fc_w, zB, out, fc_b);
}